// Round 2
// baseline (74.875 us; speedup 1.0000x reference)
//
#include <hip/hip_runtime.h>
#include <math.h>

// Problem constants (hardcoded in reference)
#define V 2048
#define DF 128
#define NK 73          // 1 + J + J^2 = 1 + 8 + 64 branch outputs
#define NSLICE 16      // v-dimension slices for k_scatter parallelism
#define A_F 0.34657359027997264f   // A = R*ln(2)/(J-R+1) = 3*ln2/6 = ln2/2
#define TWO_PI_F 6.283185307179586f

// One block per graph node v: deg[v] = rowsum(W), then the J=8 filter
// responses evaluated at eigenvalue E = deg/max(1,deg). The reference's
// Lmat = diag(deg)*dhalf*dhalf^T is EXACTLY diagonal (jnp.diag off-diagonals
// are exact zeros), so eigh returns a signed permutation and every filter
// matrix g_j = V diag(lam_j) V^T is diagonal with entry h_j(deg[v]).
__global__ __launch_bounds__(256) void k_filters(const float* __restrict__ W,
                                                 float* __restrict__ c) {
    __shared__ float red[4];
    const int v = blockIdx.x;
    const int tid = threadIdx.x;
    // row = 2048 fp32 = 512 float4; 256 threads * 2 float4 each, coalesced
    const float4* row = (const float4*)(W + (size_t)v * V);
    float4 a = row[tid];
    float4 b = row[tid + 256];
    float s = ((a.x + a.y) + (a.z + a.w)) + ((b.x + b.y) + (b.z + b.w));
    #pragma unroll
    for (int off = 32; off > 0; off >>= 1) s += __shfl_down(s, off, 64);
    if ((tid & 63) == 0) red[tid >> 6] = s;
    __syncthreads();
    if (tid == 0) {
        float deg = (red[0] + red[1]) + (red[2] + red[3]);
        // Lmat[v,v] = deg / max(1, deg);  E = |eigenvalue|
        float e = fabsf(deg / fmaxf(1.0f, deg));
        float x = logf(e);
        float sumsq = 0.0f;
        float wav[7];
        #pragma unroll
        for (int j = 2; j <= 8; ++j) {
            float t = x - A_F * (float)(j - 1) * (1.0f / 3.0f);  // R = 3
            float val = 0.0f;
            if (t > -A_F && t <= 0.0f) {
                // g_hat: 0.5*cos(0) + 0.5*cos(2*pi*(t/A + 0.5))
                val = 0.5f + 0.5f * cosf(TWO_PI_F * (t / A_F + 0.5f));
            }
            wav[j - 2] = val;
            sumsq += val * val;
        }
        // s = (R/2)(d0^2+d1^2) + (R/2)d0^2 - sum wav^2 = 1.125 - sum
        c[v] = sqrtf(fmaxf(1.125f - sumsq, 0.0f));   // scaling row (j index 0)
        #pragma unroll
        for (int j = 0; j < 7; ++j) c[(j + 1) * V + v] = wav[j];
    }
}

// grid (NK branches, NSLICE v-slices) x 128 threads (one per feature d).
// Branch k: k=0 -> plain mean of f; k=1..8 -> c_{k-1}*|f|; k>=9 -> c_j1*c_j2*|f|.
// (wavelet/scaling responses are >=0, so |c*f| = c*|f| and the two-layer
// branch is c_u*c_j*|f|; the (u,j) tensor is symmetric so ordering is safe.)
__global__ __launch_bounds__(128) void k_scatter(const float* __restrict__ f,
                                                 const float* __restrict__ c,
                                                 float* __restrict__ part) {
    const int k = blockIdx.x;
    const int sl = blockIdx.y;
    const int d = threadIdx.x;
    const int v0 = sl * (V / NSLICE);
    const int v1 = v0 + (V / NSLICE);
    float acc = 0.0f;
    if (k == 0) {
        #pragma unroll 8
        for (int v = v0; v < v1; ++v)
            acc += f[(size_t)v * DF + d];
    } else if (k <= 8) {
        const float* cj = c + (k - 1) * V;
        #pragma unroll 8
        for (int v = v0; v < v1; ++v)
            acc += cj[v] * fabsf(f[(size_t)v * DF + d]);
    } else {
        const float* c1 = c + ((k - 9) >> 3) * V;  // layer-1 branch (u-major)
        const float* c2 = c + ((k - 9) & 7) * V;   // layer-2 filter
        #pragma unroll 8
        for (int v = v0; v < v1; ++v)
            acc += c1[v] * c2[v] * fabsf(f[(size_t)v * DF + d]);
    }
    part[((size_t)sl * NK + k) * DF + d] = acc;
}

// Reduce the NSLICE partials, apply mean (1/V), emit fp32.
__global__ __launch_bounds__(256) void k_reduce(const float* __restrict__ part,
                                               float* __restrict__ out) {
    const int i = blockIdx.x * 256 + threadIdx.x;
    if (i < NK * DF) {
        float s = 0.0f;
        #pragma unroll
        for (int sl = 0; sl < NSLICE; ++sl) s += part[(size_t)sl * NK * DF + i];
        out[i] = s * (1.0f / (float)V);
    }
}

extern "C" void kernel_launch(void* const* d_in, const int* in_sizes, int n_in,
                              void* d_out, int out_size, void* d_ws, size_t ws_size,
                              hipStream_t stream) {
    const float* W = (const float*)d_in[0];   // fp32 [V,V] (reference dtype)
    const float* f = (const float*)d_in[1];   // fp32 [V,DF]
    float* out = (float*)d_out;               // fp32 [NK*DF]

    float* c = (float*)d_ws;          // 8*V floats   = 64 KB
    float* part = c + 8 * V;          // NSLICE*NK*DF = 598 KB

    k_filters<<<V, 256, 0, stream>>>(W, c);
    k_scatter<<<dim3(NK, NSLICE), DF, 0, stream>>>(f, c, part);
    k_reduce<<<(NK * DF + 255) / 256, 256, 0, stream>>>(part, out);
}